// Round 2
// baseline (198.438 us; speedup 1.0000x reference)
//
#include <hip/hip_runtime.h>
#include <hip/hip_bf16.h>

#define N_NODES 100000
#define N_EDGES 3200000

#define P_PARTS 4
#define PART    25600                    // 4*25600 = 102400 >= N ; 102.4 KB LDS
#define SLICES  64
#define SLICE_E (N_EDGES / SLICES)       // 50000, %4 == 0
#define BLOCKS_H (P_PARTS * SLICES)      // 256
#define T_HIST  1024

#define PACK_BLOCKS 512
#define PACK_T      1024
#define N_QUADS     (N_EDGES / 4)        // 800000

// ---------------- workspace layout (bytes) ----------------
#define OFF_STATS 0        // double[5]     (zeroed)
#define OFF_DEG   1024     // float[102400] (zeroed)
#define OFF_ACC   410624   // float[102400]
#define OFF_DINV  820224   // float[N]
#define OFF_GS    1220224  // float[N]
#define OFF_SRC32 1620224  // int[N_EDGES]  (12.8 MB)
#define OFF_DST32 14420224 // int[N_EDGES]  (12.8 MB)
// total ~27.2 MB

// per-wave int64-vs-int32 detection: high words of first 64 int64 slots
__device__ __forceinline__ bool detect_is64(const void* ei) {
    const int* p = (const int*)ei;
    int lane = threadIdx.x & 63;
    int hi = p[2 * lane + 1];
    unsigned long long m = __ballot(hi != 0);
    return m == 0ull;  // wave-uniform
}

// ---- K1: pack edge index to int32 (coalesced, atomic-free) + BN stats ----
__global__ __launch_bounds__(PACK_T) void pack_stats_kernel(
        const float* __restrict__ x, const void* __restrict__ ei,
        double* __restrict__ stats, int* __restrict__ src32, int* __restrict__ dst32) {
    bool is64 = detect_is64(ei);
    int tid = blockIdx.x * PACK_T + threadIdx.x;

    // ---- pack: grid-stride over edge quads ----
    if (is64) {
        const long long* srcp = (const long long*)ei;
        const long long* dstp = srcp + N_EDGES;
        for (int q = tid; q < N_QUADS; q += PACK_BLOCKS * PACK_T) {
            longlong2 s01 = ((const longlong2*)srcp)[2 * q];
            longlong2 s23 = ((const longlong2*)srcp)[2 * q + 1];
            longlong2 d01 = ((const longlong2*)dstp)[2 * q];
            longlong2 d23 = ((const longlong2*)dstp)[2 * q + 1];
            int4 s4 = make_int4((int)s01.x, (int)s01.y, (int)s23.x, (int)s23.y);
            int4 d4 = make_int4((int)d01.x, (int)d01.y, (int)d23.x, (int)d23.y);
            ((int4*)src32)[q] = s4;
            ((int4*)dst32)[q] = d4;
        }
    } else {
        const int* srcp = (const int*)ei;
        const int* dstp = srcp + N_EDGES;
        for (int q = tid; q < N_QUADS; q += PACK_BLOCKS * PACK_T) {
            ((int4*)src32)[q] = ((const int4*)srcp)[q];
            ((int4*)dst32)[q] = ((const int4*)dstp)[q];
        }
    }

    // ---- stats: one node per thread (only blocks covering nodes participate) ----
    if (blockIdx.x * PACK_T < N_NODES) {
        __shared__ double sh[5][16];
        double a0 = 0, a1 = 0, a2 = 0, a3 = 0, a4 = 0;
        int n = tid;
        if (n < N_NODES) {
            float2 v = ((const float2*)x)[n];
            double x0 = v.x, x1 = v.y;
            a0 = x0; a1 = x1; a2 = x0 * x0; a3 = x1 * x1; a4 = x0 * x1;
        }
        for (int off = 32; off; off >>= 1) {
            a0 += __shfl_down(a0, off);
            a1 += __shfl_down(a1, off);
            a2 += __shfl_down(a2, off);
            a3 += __shfl_down(a3, off);
            a4 += __shfl_down(a4, off);
        }
        int w = threadIdx.x >> 6;
        if ((threadIdx.x & 63) == 0) {
            sh[0][w] = a0; sh[1][w] = a1; sh[2][w] = a2; sh[3][w] = a3; sh[4][w] = a4;
        }
        __syncthreads();
        if (threadIdx.x == 0) {
            double t0 = 0, t1 = 0, t2 = 0, t3 = 0, t4 = 0;
            for (int i = 0; i < 16; i++) {
                t0 += sh[0][i]; t1 += sh[1][i]; t2 += sh[2][i]; t3 += sh[3][i]; t4 += sh[4][i];
            }
            atomicAdd(&stats[0], t0);
            atomicAdd(&stats[1], t1);
            atomicAdd(&stats[2], t2);
            atomicAdd(&stats[3], t3);
            atomicAdd(&stats[4], t4);
        }
    }
}

// ---- K2: LDS-privatized degree histogram over packed dst32 ----
// P_PARTS=4: each edge examined by 4 blocks (was 8); 102.4 KB LDS, 1 block/CU.
__global__ __launch_bounds__(T_HIST, 4) void deg_hist_kernel(
        const int* __restrict__ dst32, float* __restrict__ degf) {
    __shared__ float hist[PART];
    int p = blockIdx.x & (P_PARTS - 1);
    int slice = blockIdx.x >> 2;
    int base = p * PART;

    for (int i = threadIdx.x; i < PART; i += T_HIST) hist[i] = 0.f;
    __syncthreads();

    int e0 = slice * SLICE_E, e1 = e0 + SLICE_E;
    for (int e = e0 + threadIdx.x * 4; e < e1; e += T_HIST * 4) {
        int4 d4 = *(const int4*)(dst32 + e);
        unsigned l0 = (unsigned)(d4.x - base);
        unsigned l1 = (unsigned)(d4.y - base);
        unsigned l2 = (unsigned)(d4.z - base);
        unsigned l3 = (unsigned)(d4.w - base);
        if (l0 < PART) atomicAdd(&hist[l0], 1.0f);
        if (l1 < PART) atomicAdd(&hist[l1], 1.0f);
        if (l2 < PART) atomicAdd(&hist[l2], 1.0f);
        if (l3 < PART) atomicAdd(&hist[l3], 1.0f);
    }
    __syncthreads();
    for (int i = threadIdx.x; i < PART; i += T_HIST) {
        float v = hist[i];
        if (v != 0.f) unsafeAtomicAdd(&degf[base + i], v);
    }
}

// ---- K3: encoder (scalar): gs[n] = dinv * (GB + sum_c PReLU(Ax0+Bx1+C) U[c]) ----
__global__ void encoder_kernel(const float* __restrict__ x,
                               const double* __restrict__ stats,
                               const float* __restrict__ w1, const float* __restrict__ b1,
                               const float* __restrict__ gamma, const float* __restrict__ beta,
                               const float* __restrict__ prelu_a,
                               const float* __restrict__ w2, const float* __restrict__ b2,
                               const float* __restrict__ gcn_w, const float* __restrict__ wb,
                               const float* __restrict__ degf,
                               float* __restrict__ dinv, float* __restrict__ gs,
                               float* __restrict__ acc) {
    __shared__ float sA[32], sB[32], sC[32], sV[32], sU[32];
    __shared__ float sGB;
    if (threadIdx.x < 32) {
        int c = threadIdx.x;
        double invN = 1.0 / (double)N_NODES;
        double m0 = stats[0] * invN, m1 = stats[1] * invN;
        double e00 = stats[2] * invN, e11 = stats[3] * invN, e01 = stats[4] * invN;
        double a = w1[2 * c], b = w1[2 * c + 1], t = b1[c];
        double meanH = a * m0 + b * m1 + t;
        double eh2 = a * a * e00 + b * b * e11 + 2.0 * a * b * e01 +
                     2.0 * t * (a * m0 + b * m1) + t * t;
        double var = eh2 - meanH * meanH;
        double inv = 1.0 / sqrt(var + 1e-5);
        float sc = (float)((double)gamma[c] * inv);
        float shift = beta[c] - (float)meanH * sc;
        sA[c] = (float)a * sc;
        sB[c] = (float)b * sc;
        sC[c] = (float)t * sc + shift;
        float vc = 0.f;
        for (int j = 0; j < 32; j++) vc += wb[j] * gcn_w[j * 32 + c];
        sV[c] = vc;
        float gb = b2[c] * vc;
        for (int off = 16; off; off >>= 1) gb += __shfl_down(gb, off, 32);
        if (c == 0) sGB = gb;
    }
    __syncthreads();
    if (threadIdx.x < 32) {
        float u = 0.f;
        for (int c = 0; c < 32; c++) u += sV[c] * w2[c * 32 + threadIdx.x];
        sU[threadIdx.x] = u;
    }
    __syncthreads();
    float alpha = prelu_a[0];
    int n = blockIdx.x * blockDim.x + threadIdx.x;
    if (n < N_NODES) {
        float2 xv = ((const float2*)x)[n];
        float g = sGB;
#pragma unroll
        for (int c = 0; c < 32; c++) {
            float hb = sA[c] * xv.x + sB[c] * xv.y + sC[c];
            float pc = hb >= 0.f ? hb : alpha * hb;
            g += pc * sU[c];
        }
        float di = rsqrtf(degf[n] + 1.0f);
        float gg = di * g;
        dinv[n] = di;
        gs[n] = gg;
        acc[n] = gg;  // self-loop term; finalize multiplies by dinv
    }
}

// ---- K4: LDS-privatized scatter over packed src32/dst32 ----
__global__ __launch_bounds__(T_HIST, 4) void scatter_hist_kernel(
        const int* __restrict__ src32, const int* __restrict__ dst32,
        const float* __restrict__ gs, float* __restrict__ acc) {
    __shared__ float hist[PART];
    int p = blockIdx.x & (P_PARTS - 1);
    int slice = blockIdx.x >> 2;
    int base = p * PART;

    for (int i = threadIdx.x; i < PART; i += T_HIST) hist[i] = 0.f;
    __syncthreads();

    int e0 = slice * SLICE_E, e1 = e0 + SLICE_E;
    for (int e = e0 + threadIdx.x * 4; e < e1; e += T_HIST * 4) {
        int4 d4 = *(const int4*)(dst32 + e);
        int4 s4 = *(const int4*)(src32 + e);
        unsigned l0 = (unsigned)(d4.x - base);
        unsigned l1 = (unsigned)(d4.y - base);
        unsigned l2 = (unsigned)(d4.z - base);
        unsigned l3 = (unsigned)(d4.w - base);
        if (l0 < PART) atomicAdd(&hist[l0], gs[s4.x]);
        if (l1 < PART) atomicAdd(&hist[l1], gs[s4.y]);
        if (l2 < PART) atomicAdd(&hist[l2], gs[s4.z]);
        if (l3 < PART) atomicAdd(&hist[l3], gs[s4.w]);
    }
    __syncthreads();
    for (int i = threadIdx.x; i < PART; i += T_HIST) {
        float v = hist[i];
        if (v != 0.f) unsafeAtomicAdd(&acc[base + i], v);
    }
}

// ---- K5: finalize: out = dinv*acc + const ----
__global__ void finalize_kernel(const float* __restrict__ dinv, const float* __restrict__ acc,
                                const float* __restrict__ gcn_b, const float* __restrict__ wb,
                                const float* __restrict__ bb, float* __restrict__ out) {
    __shared__ float scc;
    if (threadIdx.x < 32) {
        float pv = wb[threadIdx.x] * gcn_b[threadIdx.x];
        for (int off = 16; off; off >>= 1) pv += __shfl_down(pv, off, 32);
        if (threadIdx.x == 0) scc = pv + bb[0];
    }
    __syncthreads();
    int n = blockIdx.x * blockDim.x + threadIdx.x;
    if (n < N_NODES) out[n] = dinv[n] * acc[n] + scc;
}

extern "C" void kernel_launch(void* const* d_in, const int* in_sizes, int n_in,
                              void* d_out, int out_size, void* d_ws, size_t ws_size,
                              hipStream_t stream) {
    const float* x       = (const float*)d_in[0];
    const void*  ei      = d_in[1];
    const float* w1      = (const float*)d_in[2];
    const float* b1      = (const float*)d_in[3];
    const float* bn_g    = (const float*)d_in[4];
    const float* bn_b    = (const float*)d_in[5];
    const float* prelu_a = (const float*)d_in[6];
    const float* w2      = (const float*)d_in[7];
    const float* b2      = (const float*)d_in[8];
    const float* gcn_w   = (const float*)d_in[9];
    const float* gcn_b   = (const float*)d_in[10];
    const float* wb      = (const float*)d_in[11];
    const float* bb      = (const float*)d_in[12];
    float* out = (float*)d_out;

    char* base = (char*)d_ws;
    double* stats = (double*)(base + OFF_STATS);
    float*  degf  = (float*)(base + OFF_DEG);
    float*  acc   = (float*)(base + OFF_ACC);
    float*  dinv  = (float*)(base + OFF_DINV);
    float*  gs    = (float*)(base + OFF_GS);
    int*    src32 = (int*)(base + OFF_SRC32);
    int*    dst32 = (int*)(base + OFF_DST32);

    // zero stats + degf (acc fully handled by encoder + skip-zero flush)
    hipMemsetAsync(d_ws, 0, OFF_DEG + PART * P_PARTS * 4, stream);

    pack_stats_kernel<<<PACK_BLOCKS, PACK_T, 0, stream>>>(x, ei, stats, src32, dst32);
    deg_hist_kernel<<<BLOCKS_H, T_HIST, 0, stream>>>(dst32, degf);
    encoder_kernel<<<(N_NODES + 255) / 256, 256, 0, stream>>>(
        x, stats, w1, b1, bn_g, bn_b, prelu_a, w2, b2, gcn_w, wb, degf, dinv, gs, acc);
    scatter_hist_kernel<<<BLOCKS_H, T_HIST, 0, stream>>>(src32, dst32, gs, acc);
    finalize_kernel<<<(N_NODES + 255) / 256, 256, 0, stream>>>(dinv, acc, gcn_b, wb, bb, out);
}